// Round 8
// baseline (285.683 us; speedup 1.0000x reference)
//
#include <hip/hip_runtime.h>

// LSTM: B=2048, T=512, INPUT=2, H=32, OUT=1. One wave per batch element.
// Lane j owns gate rows j and j+64:
//   lanes 0..31 -> i_j, g_j ; lanes 32..63 -> f_{j-32}, o_{j-32}
// Round 8: FULL F32 recurrence (f16 storage floor measured at 1.17e-2 >
// 9.3e-3 threshold in R6/R7). h broadcast via 32 v_readlane into 64-bit
// SGPR pairs (SALU pairing, off the VALU pipe); recurrent dot =
// v_pk_fma_f32 with the h pair as the scalar src0 (VOP3P: one 64-bit
// scalar read = one constant-bus slot). No LDS h-broadcast (R4 showed the
// 8x b128 same-address reads saturated the per-CU DS pipe).

#define BB 2048
#define TT 512
#define HH 32
#define CHUNK 64
#define HROW 33   // FC-history row stride: banks (t+u)%32, 2-way = free

typedef float v2f __attribute__((ext_vector_type(2)));

__device__ __forceinline__ float sigm(float x) {
    return __builtin_amdgcn_rcpf(1.0f + __expf(-x));
}

// acc += h2 * w  (packed f32; h2 = {h_even, h_odd} in an SGPR pair)
__device__ __forceinline__ v2f pkfma_s(v2f acc, unsigned long long h2, v2f w) {
    asm("v_pk_fma_f32 %0, %1, %2, %0" : "+v"(acc) : "s"(h2), "v"(w));
    return acc;
}

__global__ __launch_bounds__(256, 2) void lstm_fused_kernel(
    const float* __restrict__ x,     // [B, T, 2]
    const float* __restrict__ W_ih,  // [128, 2]
    const float* __restrict__ W_hh,  // [128, 32]
    const float* __restrict__ b_ih,  // [128]
    const float* __restrict__ b_hh,  // [128]
    const float* __restrict__ W_fc,  // [1, 32]
    const float* __restrict__ b_fc,  // [1]
    float* __restrict__ out)         // [B, T, 1]
{
    __shared__ float lds_x[4 * TT * 2];               // 16 KB x staging
    __shared__ float lds_h[4 * (CHUNK + 1) * HROW];   // FC history + scratch row

    const int lane = threadIdx.x & 63;
    const int wv   = threadIdx.x >> 6;
    const int b    = blockIdx.x * 4 + wv;
    const bool low = (lane < 32);

    // ---- stage x[T,2] into LDS, coalesced float4 ----
    {
        const float4* xg = (const float4*)(x + (size_t)b * TT * 2);
        float4* xs = (float4*)(lds_x + wv * TT * 2);
        #pragma unroll
        for (int r = 0; r < 4; ++r) xs[r * 64 + lane] = xg[r * 64 + lane];
    }

    // ---- per-lane weights (f32 pairs for v_pk_fma_f32) ----
    const int rlo = lane, rhi = lane + 64;
    const v2f wihl = ((const v2f*)W_ih)[rlo];
    const v2f wihh = ((const v2f*)W_ih)[rhi];
    const float bl = b_ih[rlo] + b_hh[rlo];
    const float bh = b_ih[rhi] + b_hh[rhi];

    v2f wloq[HH / 2], whiq[HH / 2];
    #pragma unroll
    for (int k = 0; k < HH / 2; ++k) {
        wloq[k] = ((const v2f*)(W_hh + rlo * HH))[k];
        whiq[k] = ((const v2f*)(W_hh + rhi * HH))[k];
    }

    float wfc[HH];
    #pragma unroll
    for (int u = 0; u < HH; ++u) wfc[u] = W_fc[u];
    const float bfc = b_fc[0];

    // activation selectors: lanes<32 hi-gate = tanh (=2*sigm(2x)-1)
    const float Mm = low ? 2.0f : 1.0f;
    const float Aa = low ? 2.0f : 1.0f;
    const float Bb = low ? -1.0f : 0.0f;

    float c = 0.0f;
    unsigned long long hprev[HH / 2];   // {h2k,h2k+1} f32 pairs, wave-uniform
    #pragma unroll
    for (int k = 0; k < HH / 2; ++k) hprev[k] = 0ull;

    float* out_b = out + (size_t)b * TT;
    const v2f* xw = (const v2f*)(lds_x + wv * TT * 2);
    float* hb = lds_h + wv * (CHUNK + 1) * HROW;

    __syncthreads();

    const v2f binitL = {bl, 0.0f};
    const v2f binitH = {bh, 0.0f};

    #pragma unroll 1
    for (int ch = 0; ch < TT / CHUNK; ++ch) {
        #pragma unroll 2
        for (int u = 0; u < CHUNK; ++u) {
            v2f xt = xw[ch * CHUNK + u];

            // x-projection + bias (packed)
            v2f aL0 = __builtin_elementwise_fma(xt, wihl, binitL);
            v2f aH0 = __builtin_elementwise_fma(xt, wihh, binitH);
            v2f aL1 = {0.0f, 0.0f};
            v2f aH1 = {0.0f, 0.0f};

            // recurrent dot: 4 chains x 8 v_pk_fma_f32 (SGPR-pair h, VGPR w)
            #pragma unroll
            for (int k = 0; k < HH / 4; ++k) {
                aL0 = pkfma_s(aL0, hprev[k],          wloq[k]);
                aL1 = pkfma_s(aL1, hprev[k + HH/4],   wloq[k + HH/4]);
                aH0 = pkfma_s(aH0, hprev[k],          whiq[k]);
                aH1 = pkfma_s(aH1, hprev[k + HH/4],   whiq[k + HH/4]);
            }
            v2f aL = aL0 + aL1;
            v2f aH = aH0 + aH1;
            float glo = aL.x + aL.y;
            float ghi = aH.x + aH.y;

            float alo = sigm(glo);                      // i (low) / f (high)
            float ahi = fmaf(Aa, sigm(Mm * ghi), Bb);   // tanh g / sigmoid o

            // cross-half gate exchange, full f32
            float p0 = __shfl_xor(alo, 32);             // partner alo (f or i)
            float p1 = __shfl_xor(ahi, 32);             // partner ahi (o or g)

            float iv = low ? alo : p0;
            float fv = low ? p0  : alo;
            float gv = low ? ahi : p1;
            float ov = low ? p1  : ahi;

            c = fmaf(fv, c, iv * gv);
            float tc = fmaf(2.0f, sigm(2.0f * c), -1.0f);
            float hnew = ov * tc;                       // valid on ALL lanes

            // FC history: high lanes write row u; low lanes hit scratch row
            float* wr = low ? (hb + CHUNK * HROW + lane)
                            : (hb + u * HROW + (lane - 32));
            *wr = hnew;

            // broadcast h: 32 readlanes -> 16 x 64-bit SGPR pairs (SALU pack)
            #pragma unroll
            for (int k = 0; k < HH / 2; ++k) {
                unsigned lo32 = (unsigned)__builtin_amdgcn_readlane(
                    __float_as_int(hnew), 2 * k);
                unsigned hi32 = (unsigned)__builtin_amdgcn_readlane(
                    __float_as_int(hnew), 2 * k + 1);
                hprev[k] = ((unsigned long long)hi32 << 32) | lo32;
            }
        }

        // ---- chunk flush: FC for 64 timesteps, coalesced store ----
        float acc = bfc;
        const float* row = hb + lane * HROW;
        #pragma unroll
        for (int u2 = 0; u2 < HH; ++u2)
            acc = fmaf(row[u2], wfc[u2], acc);
        out_b[ch * CHUNK + lane] = acc;
    }
}

extern "C" void kernel_launch(void* const* d_in, const int* in_sizes, int n_in,
                              void* d_out, int out_size, void* d_ws, size_t ws_size,
                              hipStream_t stream) {
    const float* x    = (const float*)d_in[0];
    const float* W_ih = (const float*)d_in[1];
    const float* W_hh = (const float*)d_in[2];
    const float* b_ih = (const float*)d_in[3];
    const float* b_hh = (const float*)d_in[4];
    const float* W_fc = (const float*)d_in[5];
    const float* b_fc = (const float*)d_in[6];
    float* out = (float*)d_out;

    dim3 grid(BB / 4);
    dim3 block(256);
    lstm_fused_kernel<<<grid, block, 0, stream>>>(x, W_ih, W_hh, b_ih, b_hh,
                                                  W_fc, b_fc, out);
}